// Round 9
// baseline (195.090 us; speedup 1.0000x reference)
//
#include <hip/hip_runtime.h>
#include <hip/hip_bf16.h>
#include <math.h>

// MyAttentionHead: B=4, S=2048, d_model=1024, d_head=64. fp32 in/out storage.
// out = ((P~ @ xv) * 1/l) @ O^T.   4-dispatch pipeline:
// K0 wprep (QKV hi/lo transposed + O hi/lo),
// K1 qkv_fused: x @ [Q|K|V], K=1024 in-block, REG-STAGED DOUBLE-BUFFERED
//    pipeline (loads for it+1 issued before compute of it; 2 blocks/CU),
//    LDS rows padded to 40 ushorts (16B-aligned, bank-conflict-free),
// K2 attn_part: flash attention, 4-way k-split (1024 blocks) -> fp32 partial
//    O slabs [s*2+h2] + partial l [s]   (round-7 verified, unchanged),
// K3 out_fused: reduce 8 slabs (read once) + 1/l -> LDS -> hi/lo frags ->
//    GEMM vs O^T -> fp32 out  (round-8 verified, unchanged).
#define BATCH 4
#define SEQ   2048
#define DM    1024
#define DH    64
#define NROWS (BATCH*SEQ)   // 8192

typedef __hip_bfloat16 bf16;
typedef __attribute__((ext_vector_type(8))) short short8;
typedef __attribute__((ext_vector_type(8))) unsigned short ushortx8;
typedef __attribute__((ext_vector_type(4))) float floatx4;

__device__ __forceinline__ ushort f2bf(float f) {
    union { bf16 h; ushort u; } cv;
    cv.h = __float2bfloat16(f);
    return cv.u;
}
__device__ __forceinline__ float bf2f(ushort u) {
    union { unsigned int i; float f; } v; v.i = ((unsigned int)u) << 16; return v.f;
}

// async 16B global->LDS: lds dest = wave-uniform base + lane*16
__device__ __forceinline__ void load_lds16(const ushort* g, ushort* l) {
    __builtin_amdgcn_global_load_lds(
        (const __attribute__((address_space(1))) unsigned int*)g,
        (__attribute__((address_space(3))) unsigned int*)l, 16, 0, 0);
}

// ---------------- K0: weight prep ----------------
__global__ __launch_bounds__(256) void wprep_kernel(
    const float* __restrict__ Q, const float* __restrict__ K,
    const float* __restrict__ V, const float* __restrict__ O,
    ushort* __restrict__ WhT, ushort* __restrict__ WlT,
    ushort* __restrict__ Oh, ushort* __restrict__ Ol)
{
    int n = blockIdx.x;                       // 0..255
    if (n < 192) {
        const float* W = (n < 64) ? Q : (n < 128) ? K : V;
        int c = n & 63;
        for (int k = threadIdx.x; k < DM; k += 256) {
            float w = W[k * DH + c];
            ushort hi = f2bf(w);
            WhT[n * DM + k] = hi;
            WlT[n * DM + k] = f2bf(w - bf2f(hi));
        }
    } else {
        int e0 = (n - 192) << 4;              // 16 rows of O per block
        for (int idx = threadIdx.x; idx < 16 * DH; idx += 256) {
            int off = (e0 << 6) + idx;
            float w = O[off];
            ushort hi = f2bf(w);
            Oh[off] = hi;
            Ol[off] = f2bf(w - bf2f(hi));
        }
    }
}

// ---------------- K1: qkv_fused — x @ [Q|K|V], pipelined K-loop ----------------
// Block = 32 seq rows, 512 thr = 8 waves: wave = (mh = w>>2, cg = w&3).
// Reg-staged double buffer: iteration it computes from LDS buf[it&1] while
// the global loads for it+1 (issued before compute) are in flight; after the
// barrier they are converted and written to buf[(it+1)&1].
// Epilogue: hi/lo split -> qh/ql/kh/kl; v -> xvP permuted (ushort4/thread:
// k_local = mh*16+qd*4+r  ->  [c32][qd][h][mh*4+r]).
#define QPAD 40
__global__ __launch_bounds__(512) void qkv_fused_kernel(
    const float* __restrict__ x, const ushort* __restrict__ WhT,
    const ushort* __restrict__ WlT,
    ushort* __restrict__ qh, ushort* __restrict__ ql,
    ushort* __restrict__ kh, ushort* __restrict__ kl, ushort* __restrict__ xvP)
{
    __shared__ __align__(16) ushort Xs[2][2][32][QPAD];   // [buf][hl][row][k]
    __shared__ __align__(16) ushort Ws[2][2][192][QPAD];  // [buf][hl][n][k]
    int s0 = blockIdx.x * 32;
    int t = threadIdx.x;
    int wave = t >> 6, lane = t & 63, m_ = lane & 15, qd = lane >> 4;
    int mh = wave >> 2, cg = wave & 3;
    const floatx4 z4 = {0.f, 0.f, 0.f, 0.f};
    floatx4 accq = z4, acck = z4, accv = z4;
    int xr = t >> 4, xc = (t & 15) * 2;
    // W stage decode (3 x uint4 per thread)
    int widx[3], whl[3], wn[3], wkc[3];
    #pragma unroll
    for (int j = 0; j < 3; ++j) {
        int idx = t + j * 512;            // 0..1535
        whl[j] = (idx >= 768);
        int r2 = idx - whl[j] * 768;      // 0..767
        wn[j] = r2 >> 2; wkc[j] = (r2 & 3) * 8;
        widx[j] = wn[j] * DM + wkc[j];
    }
    float2 xs_reg;
    uint4 w_reg[3];
    // prologue: load + write iteration 0 into buf 0
    xs_reg = *(const float2*)&x[(size_t)(s0 + xr) * DM + xc];
    #pragma unroll
    for (int j = 0; j < 3; ++j)
        w_reg[j] = *(const uint4*)&(whl[j] ? WlT : WhT)[widx[j]];
    {
        ushort h0 = f2bf(xs_reg.x), h1 = f2bf(xs_reg.y);
        *(ushort2*)&Xs[0][0][xr][xc] = make_ushort2(h0, h1);
        *(ushort2*)&Xs[0][1][xr][xc] = make_ushort2(
            f2bf(xs_reg.x - bf2f(h0)), f2bf(xs_reg.y - bf2f(h1)));
        #pragma unroll
        for (int j = 0; j < 3; ++j)
            *(uint4*)&Ws[0][whl[j]][wn[j]][wkc[j]] = w_reg[j];
    }
    __syncthreads();
    for (int it = 0; it < 32; ++it) {
        int cur = it & 1;
        if (it < 31) {   // issue loads for it+1 (in flight during compute)
            int k0n = (it + 1) * 32;
            xs_reg = *(const float2*)&x[(size_t)(s0 + xr) * DM + k0n + xc];
            #pragma unroll
            for (int j = 0; j < 3; ++j)
                w_reg[j] = *(const uint4*)&(whl[j] ? WlT : WhT)[widx[j] + k0n];
        }
        // compute from buf[cur]
        short8 ah = *(const short8*)&Xs[cur][0][mh * 16 + m_][qd * 8];
        short8 al = *(const short8*)&Xs[cur][1][mh * 16 + m_][qd * 8];
        int nq = cg * 16 + m_, nk = 64 + cg * 16 + m_, nv = 128 + cg * 16 + m_;
        short8 bqh = *(const short8*)&Ws[cur][0][nq][qd * 8];
        short8 bql = *(const short8*)&Ws[cur][1][nq][qd * 8];
        short8 bkh = *(const short8*)&Ws[cur][0][nk][qd * 8];
        short8 bkl = *(const short8*)&Ws[cur][1][nk][qd * 8];
        short8 bvh = *(const short8*)&Ws[cur][0][nv][qd * 8];
        accq = __builtin_amdgcn_mfma_f32_16x16x32_bf16(ah, bqh, accq, 0, 0, 0);
        accq = __builtin_amdgcn_mfma_f32_16x16x32_bf16(al, bqh, accq, 0, 0, 0);
        accq = __builtin_amdgcn_mfma_f32_16x16x32_bf16(ah, bql, accq, 0, 0, 0);
        acck = __builtin_amdgcn_mfma_f32_16x16x32_bf16(ah, bkh, acck, 0, 0, 0);
        acck = __builtin_amdgcn_mfma_f32_16x16x32_bf16(al, bkh, acck, 0, 0, 0);
        acck = __builtin_amdgcn_mfma_f32_16x16x32_bf16(ah, bkl, acck, 0, 0, 0);
        accv = __builtin_amdgcn_mfma_f32_16x16x32_bf16(ah, bvh, accv, 0, 0, 0);
        __syncthreads();
        if (it < 31) {   // write staged regs into the other buffer
            int nxt = cur ^ 1;
            ushort h0 = f2bf(xs_reg.x), h1 = f2bf(xs_reg.y);
            *(ushort2*)&Xs[nxt][0][xr][xc] = make_ushort2(h0, h1);
            *(ushort2*)&Xs[nxt][1][xr][xc] = make_ushort2(
                f2bf(xs_reg.x - bf2f(h0)), f2bf(xs_reg.y - bf2f(h1)));
            #pragma unroll
            for (int j = 0; j < 3; ++j)
                *(uint4*)&Ws[nxt][whl[j]][wn[j]][wkc[j]] = w_reg[j];
        }
        __syncthreads();
    }
    // epilogue: q,k -> hi/lo row-major; v -> xvP permuted
    int col = cg * 16 + m_;
    #pragma unroll
    for (int r = 0; r < 4; ++r) {
        int row = s0 + mh * 16 + qd * 4 + r;
        ushort hq = f2bf(accq[r]);
        qh[row * 64 + col] = hq;
        ql[row * 64 + col] = f2bf(accq[r] - bf2f(hq));
        ushort hk = f2bf(acck[r]);
        kh[row * 64 + col] = hk;
        kl[row * 64 + col] = f2bf(acck[r] - bf2f(hk));
    }
    int b = s0 >> 11, c32 = (s0 & 2047) >> 5;
    ushort4 v4;
    v4.x = f2bf(accv[0]); v4.y = f2bf(accv[1]);
    v4.z = f2bf(accv[2]); v4.w = f2bf(accv[3]);
    *(ushort4*)&xvP[(size_t)(((b * 64 + c32) * 4 + qd) * 512) + col * 8 + mh * 4] = v4;
}

// ---------------- K2: attn_part — flash attention, 4-way k-split ----------------
// (round-7 verified, unchanged)
__global__ __launch_bounds__(512) void attn_part_kernel(
    const ushort* __restrict__ qh, const ushort* __restrict__ ql,
    const ushort* __restrict__ kh, const ushort* __restrict__ kl,
    const ushort* __restrict__ xvP,
    float* __restrict__ Opart, float* __restrict__ lpart)
{
    __shared__ __align__(16) ushort Kbuf[2][8192];   // [buf][hi 4096 | lo 4096]
    __shared__ __align__(16) ushort xvbuf[2][4096];  // [buf][c32sub][qd][h][j8]
    __shared__ float lred[2][2][16];                 // [tile][h2][q]
    int bid = blockIdx.x;
    int pp = bid & 63, b = (bid >> 6) & 3, s = bid >> 8;
    int srowA = pp << 4, srowB = (127 - pp) << 4;
    int t = threadIdx.x, wave = t >> 6, lane = t & 63, m_ = lane & 15, qd = lane >> 4;
    int nA = (pp >> 2) + 1, nB = ((127 - pp) >> 2) + 1;   // nA < nB always
    int tile = wave >> 2, h2 = (wave >> 1) & 1, nh = wave & 1;
    int srow = tile ? srowB : srowA;
    int nT = tile ? nB : nA;
    int jB = (nB - s + 3) >> 2;       // nB >= 17 > 3 >= s
    const ushort* khb = kh + (((size_t)b << 11)) * 64;
    const ushort* klb = kl + (((size_t)b << 11)) * 64;
    const ushort* xvPb = xvP + ((size_t)b << 17);
    // hoisted Q B-frags: bq[hl][kk]
    short8 bq[2][2];
    {
        size_t qr = (size_t)((b << 11) + srow + m_) * 64 + qd * 8;
        bq[0][0] = *(const short8*)&qh[qr];
        bq[0][1] = *(const short8*)&qh[qr + 32];
        bq[1][0] = *(const short8*)&ql[qr];
        bq[1][1] = *(const short8*)&ql[qr + 32];
    }
    int drow = lane >> 3;                 // 0..7
    int dlc = ((lane & 7) ^ drow) * 8;    // pre-swizzled 16B chunk (ushort units)
    // stage chunk cc into buf: 24 instrs (8 K-hi, 8 K-lo, 8 xv), wave does 3
    #define AT_STAGE(cc, buf)                                                   \
        { int k0r_ = (cc) << 6;                                                 \
          _Pragma("unroll")                                                     \
          for (int i_ = 0; i_ < 3; ++i_) {                                      \
              int c_ = wave * 3 + i_;                                           \
              if (c_ < 8)                                                       \
                  load_lds16(khb + (size_t)(k0r_ + c_ * 8 + drow) * 64 + dlc,   \
                             &Kbuf[buf][c_ * 512]);                             \
              else if (c_ < 16)                                                 \
                  load_lds16(klb + (size_t)(k0r_ + (c_ - 8) * 8 + drow) * 64 + dlc, \
                             &Kbuf[buf][4096 + (c_ - 8) * 512]);                \
              else                                                              \
                  load_lds16(xvPb + (size_t)(cc) * 4096 + (c_ - 16) * 512 + lane * 8, \
                             &xvbuf[buf][(c_ - 16) * 512]);                     \
          } }
    const floatx4 z4 = {0.f, 0.f, 0.f, 0.f};
    floatx4 accO[2] = {z4, z4};
    float ll = 0.f;
    int qrow = srow + m_;
    AT_STAGE(s, 0)
    for (int j = 0; j < jB; ++j) {
        int c = s + 4 * j;
        __syncthreads();
        if (j + 1 < jB) AT_STAGE(s + 4 * (j + 1), (j + 1) & 1)
        if (c < nT) {
            int bufi = j & 1;
            floatx4 accS[2] = {z4, z4};
            #pragma unroll
            for (int kk = 0; kk < 2; ++kk) {
                #pragma unroll
                for (int tt = 0; tt < 2; ++tt) {
                    int row = (2 * h2 + tt) * 16 + m_;
                    int chunk = ((kk << 2) + qd) ^ (m_ & 7);
                    const ushort* ph = &Kbuf[bufi][row * 64 + chunk * 8];
                    short8 akh = *(const short8*)ph;
                    short8 akl = *(const short8*)(ph + 4096);
                    accS[tt] = __builtin_amdgcn_mfma_f32_16x16x32_bf16(akh, bq[0][kk], accS[tt], 0, 0, 0);
                    accS[tt] = __builtin_amdgcn_mfma_f32_16x16x32_bf16(akl, bq[0][kk], accS[tt], 0, 0, 0);
                    accS[tt] = __builtin_amdgcn_mfma_f32_16x16x32_bf16(akh, bq[1][kk], accS[tt], 0, 0, 0);
                }
            }
            float lsum = 0.f;
            short8 pa;
            #pragma unroll
            for (int tt = 0; tt < 2; ++tt) {
                #pragma unroll
                for (int r = 0; r < 4; ++r) {
                    int kc = c * 64 + (2 * h2 + tt) * 16 + qd * 4 + r;
                    float p = (kc <= qrow) ? __expf(accS[tt][r]) : 0.f;
                    lsum += p;
                    pa[tt * 4 + r] = (short)f2bf(p);
                }
            }
            if (nh == 0) ll += lsum;
            const ushort* Xb = &xvbuf[bufi][(h2 * 4 + qd) * 512];
            #pragma unroll
            for (int i = 0; i < 2; ++i) {
                int h = (nh * 2 + i) * 16 + m_;
                short8 xv = *(const short8*)&Xb[h * 8];
                accO[i] = __builtin_amdgcn_mfma_f32_16x16x32_bf16(pa, xv, accO[i], 0, 0, 0);
            }
        }
    }
    // l partial: reduce over qd lanes; (tile,h2) slot from nh==0 waves
    ll += __shfl_xor(ll, 16); ll += __shfl_xor(ll, 32);
    if (qd == 0 && nh == 0) lred[tile][h2][m_] = ll;
    __syncthreads();
    if (t < 32) {
        int tl = t >> 4, q = t & 15;
        int row = (b << 11) + (tl ? srowB : srowA) + q;
        lpart[(size_t)s * NROWS + row] = lred[tl][0][q] + lred[tl][1][q];
    }
    // O partial slab sp = s*2+h2 (disjoint rows/cols per block/wave)
    float* OP = Opart + ((size_t)(s * 2 + h2) * NROWS + (b << 11) + srow) * 64;
    #pragma unroll
    for (int i = 0; i < 2; ++i)
        #pragma unroll
        for (int r = 0; r < 4; ++r)
            OP[(qd * 4 + r) * 64 + (nh * 2 + i) * 16 + m_] = accO[i][r];
    #undef AT_STAGE
}

// ---------------- K3: out_fused — reduce slabs + 1/l, GEMM vs O^T ----------------
// (round-8 verified, unchanged)
__global__ __launch_bounds__(512) void out_fused_kernel(
    const float* __restrict__ Opart, const float* __restrict__ lpart,
    const ushort* __restrict__ Oh, const ushort* __restrict__ Ol,
    float* __restrict__ out)
{
    __shared__ float Axv[16][68];
    __shared__ float lsc[16];
    int r0 = blockIdx.x * 16;
    int t = threadIdx.x;
    if (t < 16) {
        int rg = r0 + t;
        lsc[t] = 1.f / (lpart[rg] + lpart[NROWS + rg]
                      + lpart[2 * NROWS + rg] + lpart[3 * NROWS + rg]);
    }
    __syncthreads();
    {
        const size_t PSL = (size_t)NROWS * DH;
        size_t e = (size_t)r0 * 64 + t * 2;
        float2 a = *(const float2*)&Opart[e];
        #pragma unroll
        for (int sp = 1; sp < 8; ++sp) {
            float2 w = *(const float2*)&Opart[sp * PSL + e];
            a.x += w.x; a.y += w.y;
        }
        int rr = t >> 5;                 // local row (t*2/64)
        float sc = lsc[rr];
        Axv[rr][(t & 31) * 2]     = a.x * sc;
        Axv[rr][(t & 31) * 2 + 1] = a.y * sc;
    }
    __syncthreads();
    int wave = t >> 6, lane = t & 63, m_ = lane & 15, qd = lane >> 4;
    int e0w = wave << 7;
    short8 Ah[2], Al[2];
    #pragma unroll
    for (int kk = 0; kk < 2; ++kk)
        #pragma unroll
        for (int j = 0; j < 8; ++j) {
            float vv = Axv[m_][kk * 32 + qd * 8 + j];
            ushort hv = f2bf(vv);
            Ah[kk][j] = (short)hv;
            Al[kk][j] = (short)f2bf(vv - bf2f(hv));
        }
    const floatx4 z4 = {0.f, 0.f, 0.f, 0.f};
    floatx4 acc[8] = {z4, z4, z4, z4, z4, z4, z4, z4};
    #pragma unroll
    for (int ni = 0; ni < 8; ++ni) {
        #pragma unroll
        for (int kk = 0; kk < 2; ++kk) {
            size_t boff = (size_t)(e0w + ni * 16 + m_) * 64 + kk * 32 + qd * 8;
            short8 bh = *(const short8*)&Oh[boff];
            short8 bl = *(const short8*)&Ol[boff];
            acc[ni] = __builtin_amdgcn_mfma_f32_16x16x32_bf16(Ah[kk], bh, acc[ni], 0, 0, 0);
            acc[ni] = __builtin_amdgcn_mfma_f32_16x16x32_bf16(Al[kk], bh, acc[ni], 0, 0, 0);
            acc[ni] = __builtin_amdgcn_mfma_f32_16x16x32_bf16(Ah[kk], bl, acc[ni], 0, 0, 0);
        }
    }
    #pragma unroll
    for (int r = 0; r < 4; ++r) {
        float* orow = out + (size_t)(r0 + qd * 4 + r) * DM + e0w;
        #pragma unroll
        for (int ni = 0; ni < 8; ++ni)
            orow[ni * 16 + m_] = acc[ni][r];
    }
}

extern "C" void kernel_launch(void* const* d_in, const int* in_sizes, int n_in,
                              void* d_out, int out_size, void* d_ws, size_t ws_size,
                              hipStream_t stream) {
    const float* x = (const float*)d_in[0];
    const float* Q = (const float*)d_in[1];
    const float* K = (const float*)d_in[2];
    const float* V = (const float*)d_in[3];
    const float* O = (const float*)d_in[4];
    float* out = (float*)d_out;

    char* ws = (char*)d_ws;
    ushort* qh   = (ushort*)(ws);                    // 1 MB [8192][64] bf16
    ushort* ql   = (ushort*)(ws + (1ull  << 20));
    ushort* kh   = (ushort*)(ws + (2ull  << 20));
    ushort* kl   = (ushort*)(ws + (3ull  << 20));
    ushort* xvP  = (ushort*)(ws + (4ull  << 20));    // 1 MB [4][64][4][64][8] permuted xv
    ushort* WhT  = (ushort*)(ws + (5ull  << 20));    // 384 KB [192][1024]
    ushort* WlT  = (ushort*)(ws + (5ull  << 20) + (512ull << 10));
    float*  lpart = (float*)(ws + (6ull  << 20));    // 128 KB [4][8192]
    ushort* Oh   = (ushort*)(ws + (6ull  << 20) + (256ull << 10));  // 128 KB [1024][64]
    ushort* Ol   = (ushort*)(ws + (6ull  << 20) + (384ull << 10));  // 128 KB
    float*  Opart = (float*)(ws + (7ull << 20));     // 16 MB [8][8192][64] fp32

    wprep_kernel<<<256, 256, 0, stream>>>(Q, K, V, O, WhT, WlT, Oh, Ol);
    qkv_fused_kernel<<<NROWS / 32, 512, 0, stream>>>(x, WhT, WlT, qh, ql, kh, kl, xvP);
    attn_part_kernel<<<64 * BATCH * 4, 512, 0, stream>>>(qh, ql, kh, kl, xvP, Opart, lpart);
    out_fused_kernel<<<NROWS / 16, 512, 0, stream>>>(Opart, lpart, Oh, Ol, out);
}

// Round 10
// 169.652 us; speedup vs baseline: 1.1499x; 1.1499x over previous
//
#include <hip/hip_runtime.h>
#include <hip/hip_bf16.h>
#include <math.h>

// MyAttentionHead: B=4, S=2048, d_model=1024, d_head=64. fp32 in/out storage.
// out = ((P~ @ xv) * 1/l) @ O^T.   5-dispatch pipeline, all pieces verified:
// K0 wprep (QKV hi/lo transposed + O hi/lo)          [r7],
// K1a qkv_part MFMA (K-split 4 -> Cpart)             [r7],
// K1b qkv_reduce (+xv permuted to B-frag order)      [r7],
// K2 attn_part: flash attention, 4-way k-split -> fp32 O slabs + l  [r7],
// K3 out_fused: reduce 8 slabs (read once) + 1/l -> GEMM vs O^T     [r8].
#define BATCH 4
#define SEQ   2048
#define DM    1024
#define DH    64
#define NROWS (BATCH*SEQ)   // 8192

typedef __hip_bfloat16 bf16;
typedef __attribute__((ext_vector_type(8))) short short8;
typedef __attribute__((ext_vector_type(8))) unsigned short ushortx8;
typedef __attribute__((ext_vector_type(4))) float floatx4;

__device__ __forceinline__ ushort f2bf(float f) {
    union { bf16 h; ushort u; } cv;
    cv.h = __float2bfloat16(f);
    return cv.u;
}
__device__ __forceinline__ float bf2f(ushort u) {
    union { unsigned int i; float f; } v; v.i = ((unsigned int)u) << 16; return v.f;
}

// async 16B global->LDS: lds dest = wave-uniform base + lane*16
__device__ __forceinline__ void load_lds16(const ushort* g, ushort* l) {
    __builtin_amdgcn_global_load_lds(
        (const __attribute__((address_space(1))) unsigned int*)g,
        (__attribute__((address_space(3))) unsigned int*)l, 16, 0, 0);
}

// ---------------- K0: weight prep ----------------
__global__ __launch_bounds__(256) void wprep_kernel(
    const float* __restrict__ Q, const float* __restrict__ K,
    const float* __restrict__ V, const float* __restrict__ O,
    ushort* __restrict__ WhT, ushort* __restrict__ WlT,
    ushort* __restrict__ Oh, ushort* __restrict__ Ol)
{
    int n = blockIdx.x;                       // 0..255
    if (n < 192) {
        const float* W = (n < 64) ? Q : (n < 128) ? K : V;
        int c = n & 63;
        for (int k = threadIdx.x; k < DM; k += 256) {
            float w = W[k * DH + c];
            ushort hi = f2bf(w);
            WhT[n * DM + k] = hi;
            WlT[n * DM + k] = f2bf(w - bf2f(hi));
        }
    } else {
        int e0 = (n - 192) << 4;              // 16 rows of O per block
        for (int idx = threadIdx.x; idx < 16 * DH; idx += 256) {
            int off = (e0 << 6) + idx;
            float w = O[off];
            ushort hi = f2bf(w);
            Oh[off] = hi;
            Ol[off] = f2bf(w - bf2f(hi));
        }
    }
}

// ---------------- K1a: qkv partial MFMA (K-split 4) ----------------
__global__ __launch_bounds__(256) void qkv_part_kernel(
    const float* __restrict__ x, const ushort* __restrict__ WhT,
    const ushort* __restrict__ WlT, float* __restrict__ Cpart)
{
    __shared__ __align__(16) ushort Xs[2][32][34];
    __shared__ __align__(16) ushort Ws[2][192][34];
    int s0 = blockIdx.x * 32;
    int kb = blockIdx.y * 256;
    int t = threadIdx.x;
    int wave = t >> 6, lane = t & 63, m_ = lane & 15, qd = lane >> 4;
    const floatx4 z4 = {0.f, 0.f, 0.f, 0.f};
    floatx4 accq[2] = {z4, z4}, acck[2] = {z4, z4}, accv[2] = {z4, z4};
    int xr = t >> 3, xc = (t & 7) * 4;
    for (int k0 = 0; k0 < 256; k0 += 32) {
        float4 v = *(const float4*)&x[(size_t)(s0 + xr) * DM + kb + k0 + xc];
        ushort h0 = f2bf(v.x), h1 = f2bf(v.y), h2 = f2bf(v.z), h3 = f2bf(v.w);
        *(ushort4*)&Xs[0][xr][xc] = make_ushort4(h0, h1, h2, h3);
        *(ushort4*)&Xs[1][xr][xc] = make_ushort4(
            f2bf(v.x - bf2f(h0)), f2bf(v.y - bf2f(h1)),
            f2bf(v.z - bf2f(h2)), f2bf(v.w - bf2f(h3)));
        #pragma unroll
        for (int j = 0; j < 3; ++j) {
            int idx = t + j * 256, n = idx >> 2, kc = (idx & 3) * 8;
            *(uint4*)&Ws[0][n][kc] = *(const uint4*)&WhT[n * DM + kb + k0 + kc];
            *(uint4*)&Ws[1][n][kc] = *(const uint4*)&WlT[n * DM + kb + k0 + kc];
        }
        __syncthreads();
        short8 ah[2], al[2];
        #pragma unroll
        for (int mi = 0; mi < 2; ++mi) {
            ah[mi] = *(const short8*)&Xs[0][mi * 16 + m_][qd * 8];
            al[mi] = *(const short8*)&Xs[1][mi * 16 + m_][qd * 8];
        }
        int nq = wave * 16 + m_, nk = 64 + wave * 16 + m_, nv = 128 + wave * 16 + m_;
        short8 bqh = *(const short8*)&Ws[0][nq][qd * 8];
        short8 bql = *(const short8*)&Ws[1][nq][qd * 8];
        short8 bkh = *(const short8*)&Ws[0][nk][qd * 8];
        short8 bkl = *(const short8*)&Ws[1][nk][qd * 8];
        short8 bvh = *(const short8*)&Ws[0][nv][qd * 8];
        #pragma unroll
        for (int mi = 0; mi < 2; ++mi) {
            accq[mi] = __builtin_amdgcn_mfma_f32_16x16x32_bf16(ah[mi], bqh, accq[mi], 0, 0, 0);
            accq[mi] = __builtin_amdgcn_mfma_f32_16x16x32_bf16(al[mi], bqh, accq[mi], 0, 0, 0);
            accq[mi] = __builtin_amdgcn_mfma_f32_16x16x32_bf16(ah[mi], bql, accq[mi], 0, 0, 0);
            acck[mi] = __builtin_amdgcn_mfma_f32_16x16x32_bf16(ah[mi], bkh, acck[mi], 0, 0, 0);
            acck[mi] = __builtin_amdgcn_mfma_f32_16x16x32_bf16(al[mi], bkh, acck[mi], 0, 0, 0);
            acck[mi] = __builtin_amdgcn_mfma_f32_16x16x32_bf16(ah[mi], bkl, acck[mi], 0, 0, 0);
            accv[mi] = __builtin_amdgcn_mfma_f32_16x16x32_bf16(ah[mi], bvh, accv[mi], 0, 0, 0);
        }
        __syncthreads();
    }
    float* Cp = Cpart + (size_t)blockIdx.y * (NROWS * 192);
    #pragma unroll
    for (int mi = 0; mi < 2; ++mi) {
        #pragma unroll
        for (int r = 0; r < 4; ++r) {
            int row = s0 + mi * 16 + qd * 4 + r;
            float* base = Cp + (size_t)row * 192;
            base[wave * 16 + m_]       = accq[mi][r];
            base[64 + wave * 16 + m_]  = acck[mi][r];
            base[128 + wave * 16 + m_] = accv[mi][r];
        }
    }
}

// ---------------- K1b: reduce partials, split hi/lo, permute xv ----------------
// xvP layout [b][c32][qd][h][j8]: element = xv[c32*32 + 16*(j>>2) + 4*qd + (j&3)][h].
__global__ __launch_bounds__(256) void qkv_reduce_kernel(
    const float* __restrict__ Cpart,
    ushort* __restrict__ qh, ushort* __restrict__ ql,
    ushort* __restrict__ kh, ushort* __restrict__ kl, ushort* __restrict__ xvP)
{
    __shared__ ushort xvs[32][72];
    const size_t SL = (size_t)NROWS * 192;
    int row0 = blockIdx.x * 32;
    int t = threadIdx.x;
    #pragma unroll
    for (int i = 0; i < 24; ++i) {
        int e = i * 256 + t;
        int r = e / 192, c = e - r * 192;
        size_t row = row0 + r;
        size_t off = row * 192 + c;
        float s = Cpart[off] + Cpart[SL + off] + Cpart[2 * SL + off] + Cpart[3 * SL + off];
        ushort hi = f2bf(s);
        if (c < 64) {
            qh[row * 64 + c] = hi; ql[row * 64 + c] = f2bf(s - bf2f(hi));
        } else if (c < 128) {
            kh[row * 64 + c - 64] = hi; kl[row * 64 + c - 64] = f2bf(s - bf2f(hi));
        } else {
            xvs[r][c - 128] = hi;
        }
    }
    __syncthreads();
    int h = t & 63, qd = t >> 6;          // 4 waves <-> qd 0..3
    ushortx8 v;
    #pragma unroll
    for (int j = 0; j < 8; ++j)
        v[j] = xvs[4 * qd + (j & 3) + ((j >> 2) << 4)][h];
    int b = row0 >> 11, c32 = (row0 & 2047) >> 5;
    *(ushortx8*)&xvP[((((size_t)b << 6) + c32) * 4 + qd) * 512 + h * 8] = v;
}

// ---------------- K2: attn_part — flash attention, 4-way k-split ----------------
// (round-7 verified, unchanged)
__global__ __launch_bounds__(512) void attn_part_kernel(
    const ushort* __restrict__ qh, const ushort* __restrict__ ql,
    const ushort* __restrict__ kh, const ushort* __restrict__ kl,
    const ushort* __restrict__ xvP,
    float* __restrict__ Opart, float* __restrict__ lpart)
{
    __shared__ __align__(16) ushort Kbuf[2][8192];   // [buf][hi 4096 | lo 4096]
    __shared__ __align__(16) ushort xvbuf[2][4096];  // [buf][c32sub][qd][h][j8]
    __shared__ float lred[2][2][16];                 // [tile][h2][q]
    int bid = blockIdx.x;
    int pp = bid & 63, b = (bid >> 6) & 3, s = bid >> 8;
    int srowA = pp << 4, srowB = (127 - pp) << 4;
    int t = threadIdx.x, wave = t >> 6, lane = t & 63, m_ = lane & 15, qd = lane >> 4;
    int nA = (pp >> 2) + 1, nB = ((127 - pp) >> 2) + 1;   // nA < nB always
    int tile = wave >> 2, h2 = (wave >> 1) & 1, nh = wave & 1;
    int srow = tile ? srowB : srowA;
    int nT = tile ? nB : nA;
    int jB = (nB - s + 3) >> 2;       // nB >= 17 > 3 >= s
    const ushort* khb = kh + (((size_t)b << 11)) * 64;
    const ushort* klb = kl + (((size_t)b << 11)) * 64;
    const ushort* xvPb = xvP + ((size_t)b << 17);
    // hoisted Q B-frags: bq[hl][kk]
    short8 bq[2][2];
    {
        size_t qr = (size_t)((b << 11) + srow + m_) * 64 + qd * 8;
        bq[0][0] = *(const short8*)&qh[qr];
        bq[0][1] = *(const short8*)&qh[qr + 32];
        bq[1][0] = *(const short8*)&ql[qr];
        bq[1][1] = *(const short8*)&ql[qr + 32];
    }
    int drow = lane >> 3;                 // 0..7
    int dlc = ((lane & 7) ^ drow) * 8;    // pre-swizzled 16B chunk (ushort units)
    // stage chunk cc into buf: 24 instrs (8 K-hi, 8 K-lo, 8 xv), wave does 3
    #define AT_STAGE(cc, buf)                                                   \
        { int k0r_ = (cc) << 6;                                                 \
          _Pragma("unroll")                                                     \
          for (int i_ = 0; i_ < 3; ++i_) {                                      \
              int c_ = wave * 3 + i_;                                           \
              if (c_ < 8)                                                       \
                  load_lds16(khb + (size_t)(k0r_ + c_ * 8 + drow) * 64 + dlc,   \
                             &Kbuf[buf][c_ * 512]);                             \
              else if (c_ < 16)                                                 \
                  load_lds16(klb + (size_t)(k0r_ + (c_ - 8) * 8 + drow) * 64 + dlc, \
                             &Kbuf[buf][4096 + (c_ - 8) * 512]);                \
              else                                                              \
                  load_lds16(xvPb + (size_t)(cc) * 4096 + (c_ - 16) * 512 + lane * 8, \
                             &xvbuf[buf][(c_ - 16) * 512]);                     \
          } }
    const floatx4 z4 = {0.f, 0.f, 0.f, 0.f};
    floatx4 accO[2] = {z4, z4};
    float ll = 0.f;
    int qrow = srow + m_;
    AT_STAGE(s, 0)
    for (int j = 0; j < jB; ++j) {
        int c = s + 4 * j;
        __syncthreads();
        if (j + 1 < jB) AT_STAGE(s + 4 * (j + 1), (j + 1) & 1)
        if (c < nT) {
            int bufi = j & 1;
            floatx4 accS[2] = {z4, z4};
            #pragma unroll
            for (int kk = 0; kk < 2; ++kk) {
                #pragma unroll
                for (int tt = 0; tt < 2; ++tt) {
                    int row = (2 * h2 + tt) * 16 + m_;
                    int chunk = ((kk << 2) + qd) ^ (m_ & 7);
                    const ushort* ph = &Kbuf[bufi][row * 64 + chunk * 8];
                    short8 akh = *(const short8*)ph;
                    short8 akl = *(const short8*)(ph + 4096);
                    accS[tt] = __builtin_amdgcn_mfma_f32_16x16x32_bf16(akh, bq[0][kk], accS[tt], 0, 0, 0);
                    accS[tt] = __builtin_amdgcn_mfma_f32_16x16x32_bf16(akl, bq[0][kk], accS[tt], 0, 0, 0);
                    accS[tt] = __builtin_amdgcn_mfma_f32_16x16x32_bf16(akh, bq[1][kk], accS[tt], 0, 0, 0);
                }
            }
            float lsum = 0.f;
            short8 pa;
            #pragma unroll
            for (int tt = 0; tt < 2; ++tt) {
                #pragma unroll
                for (int r = 0; r < 4; ++r) {
                    int kc = c * 64 + (2 * h2 + tt) * 16 + qd * 4 + r;
                    float p = (kc <= qrow) ? __expf(accS[tt][r]) : 0.f;
                    lsum += p;
                    pa[tt * 4 + r] = (short)f2bf(p);
                }
            }
            if (nh == 0) ll += lsum;
            const ushort* Xb = &xvbuf[bufi][(h2 * 4 + qd) * 512];
            #pragma unroll
            for (int i = 0; i < 2; ++i) {
                int h = (nh * 2 + i) * 16 + m_;
                short8 xv = *(const short8*)&Xb[h * 8];
                accO[i] = __builtin_amdgcn_mfma_f32_16x16x32_bf16(pa, xv, accO[i], 0, 0, 0);
            }
        }
    }
    // l partial: reduce over qd lanes; (tile,h2) slot from nh==0 waves
    ll += __shfl_xor(ll, 16); ll += __shfl_xor(ll, 32);
    if (qd == 0 && nh == 0) lred[tile][h2][m_] = ll;
    __syncthreads();
    if (t < 32) {
        int tl = t >> 4, q = t & 15;
        int row = (b << 11) + (tl ? srowB : srowA) + q;
        lpart[(size_t)s * NROWS + row] = lred[tl][0][q] + lred[tl][1][q];
    }
    // O partial slab sp = s*2+h2 (disjoint rows/cols per block/wave)
    float* OP = Opart + ((size_t)(s * 2 + h2) * NROWS + (b << 11) + srow) * 64;
    #pragma unroll
    for (int i = 0; i < 2; ++i)
        #pragma unroll
        for (int r = 0; r < 4; ++r)
            OP[(qd * 4 + r) * 64 + (nh * 2 + i) * 16 + m_] = accO[i][r];
    #undef AT_STAGE
}

// ---------------- K3: out_fused — reduce slabs + 1/l, GEMM vs O^T ----------------
// (round-8 verified, unchanged)
__global__ __launch_bounds__(512) void out_fused_kernel(
    const float* __restrict__ Opart, const float* __restrict__ lpart,
    const ushort* __restrict__ Oh, const ushort* __restrict__ Ol,
    float* __restrict__ out)
{
    __shared__ float Axv[16][68];
    __shared__ float lsc[16];
    int r0 = blockIdx.x * 16;
    int t = threadIdx.x;
    if (t < 16) {
        int rg = r0 + t;
        lsc[t] = 1.f / (lpart[rg] + lpart[NROWS + rg]
                      + lpart[2 * NROWS + rg] + lpart[3 * NROWS + rg]);
    }
    __syncthreads();
    {
        const size_t PSL = (size_t)NROWS * DH;
        size_t e = (size_t)r0 * 64 + t * 2;
        float2 a = *(const float2*)&Opart[e];
        #pragma unroll
        for (int sp = 1; sp < 8; ++sp) {
            float2 w = *(const float2*)&Opart[sp * PSL + e];
            a.x += w.x; a.y += w.y;
        }
        int rr = t >> 5;                 // local row (t*2/64)
        float sc = lsc[rr];
        Axv[rr][(t & 31) * 2]     = a.x * sc;
        Axv[rr][(t & 31) * 2 + 1] = a.y * sc;
    }
    __syncthreads();
    int wave = t >> 6, lane = t & 63, m_ = lane & 15, qd = lane >> 4;
    int e0w = wave << 7;
    short8 Ah[2], Al[2];
    #pragma unroll
    for (int kk = 0; kk < 2; ++kk)
        #pragma unroll
        for (int j = 0; j < 8; ++j) {
            float vv = Axv[m_][kk * 32 + qd * 8 + j];
            ushort hv = f2bf(vv);
            Ah[kk][j] = (short)hv;
            Al[kk][j] = (short)f2bf(vv - bf2f(hv));
        }
    const floatx4 z4 = {0.f, 0.f, 0.f, 0.f};
    floatx4 acc[8] = {z4, z4, z4, z4, z4, z4, z4, z4};
    #pragma unroll
    for (int ni = 0; ni < 8; ++ni) {
        #pragma unroll
        for (int kk = 0; kk < 2; ++kk) {
            size_t boff = (size_t)(e0w + ni * 16 + m_) * 64 + kk * 32 + qd * 8;
            short8 bh = *(const short8*)&Oh[boff];
            short8 bl = *(const short8*)&Ol[boff];
            acc[ni] = __builtin_amdgcn_mfma_f32_16x16x32_bf16(Ah[kk], bh, acc[ni], 0, 0, 0);
            acc[ni] = __builtin_amdgcn_mfma_f32_16x16x32_bf16(Al[kk], bh, acc[ni], 0, 0, 0);
            acc[ni] = __builtin_amdgcn_mfma_f32_16x16x32_bf16(Ah[kk], bl, acc[ni], 0, 0, 0);
        }
    }
    #pragma unroll
    for (int r = 0; r < 4; ++r) {
        float* orow = out + (size_t)(r0 + qd * 4 + r) * DM + e0w;
        #pragma unroll
        for (int ni = 0; ni < 8; ++ni)
            orow[ni * 16 + m_] = acc[ni][r];
    }
}

extern "C" void kernel_launch(void* const* d_in, const int* in_sizes, int n_in,
                              void* d_out, int out_size, void* d_ws, size_t ws_size,
                              hipStream_t stream) {
    const float* x = (const float*)d_in[0];
    const float* Q = (const float*)d_in[1];
    const float* K = (const float*)d_in[2];
    const float* V = (const float*)d_in[3];
    const float* O = (const float*)d_in[4];
    float* out = (float*)d_out;

    char* ws = (char*)d_ws;
    ushort* qh   = (ushort*)(ws);                    // 1 MB [8192][64] bf16
    ushort* ql   = (ushort*)(ws + (1ull  << 20));
    ushort* kh   = (ushort*)(ws + (2ull  << 20));
    ushort* kl   = (ushort*)(ws + (3ull  << 20));
    ushort* xvP  = (ushort*)(ws + (4ull  << 20));    // 1 MB [4][64][4][64][8] permuted xv
    ushort* WhT  = (ushort*)(ws + (5ull  << 20));    // 384 KB [192][1024]
    ushort* WlT  = (ushort*)(ws + (5ull  << 20) + (512ull << 10));
    float*  lpart = (float*)(ws + (6ull  << 20));    // 128 KB [4][8192]
    ushort* Oh   = (ushort*)(ws + (6ull  << 20) + (256ull << 10));  // 128 KB [1024][64]
    ushort* Ol   = (ushort*)(ws + (6ull  << 20) + (384ull << 10));  // 128 KB
    float*  Opart = (float*)(ws + (7ull << 20));     // 16 MB [8][8192][64] fp32
    float*  Cpart = (float*)(ws + (23ull << 20));    // 25 MB [4][8192][192]

    wprep_kernel<<<256, 256, 0, stream>>>(Q, K, V, O, WhT, WlT, Oh, Ol);
    qkv_part_kernel<<<dim3(NROWS / 32, 4), 256, 0, stream>>>(x, WhT, WlT, Cpart);
    qkv_reduce_kernel<<<NROWS / 32, 256, 0, stream>>>(Cpart, qh, ql, kh, kl, xvP);
    attn_part_kernel<<<64 * BATCH * 4, 512, 0, stream>>>(qh, ql, kh, kl, xvP, Opart, lpart);
    out_fused_kernel<<<NROWS / 16, 512, 0, stream>>>(Opart, lpart, Oh, Ol, out);
}

// Round 11
// 156.040 us; speedup vs baseline: 1.2503x; 1.0872x over previous
//
#include <hip/hip_runtime.h>
#include <hip/hip_bf16.h>
#include <math.h>

// MyAttentionHead: B=4, S=2048, d_model=1024, d_head=64. fp32 in/out storage.
// out = ((P~ @ xv) * 1/l) @ O^T.   6-dispatch pipeline (r7 structure):
// K0 wprep (QKV hi/lo transposed + O hi/lo)            [r7],
// K1a qkv_part MFMA, 64-ROW blocks (halved W re-staging; K-split 4) [new],
// K1b qkv_reduce (+xv permuted to B-frag order)        [r7],
// K2 attn_part: flash attention, 4-way k-split -> fp32 O slabs + l  [r7],
// K2b axv_reduce: fold 8 slabs + 1/l -> bf16 hi/lo     [r7],
// K3 out_kernel: bf16 hi/lo GEMM [8192,64]@[64,1024]   [r7].
#define BATCH 4
#define SEQ   2048
#define DM    1024
#define DH    64
#define NROWS (BATCH*SEQ)   // 8192
#define PVSPLIT 8

typedef __hip_bfloat16 bf16;
typedef __attribute__((ext_vector_type(8))) short short8;
typedef __attribute__((ext_vector_type(8))) unsigned short ushortx8;
typedef __attribute__((ext_vector_type(4))) float floatx4;

__device__ __forceinline__ ushort f2bf(float f) {
    union { bf16 h; ushort u; } cv;
    cv.h = __float2bfloat16(f);
    return cv.u;
}
__device__ __forceinline__ float bf2f(ushort u) {
    union { unsigned int i; float f; } v; v.i = ((unsigned int)u) << 16; return v.f;
}

// async 16B global->LDS: lds dest = wave-uniform base + lane*16
__device__ __forceinline__ void load_lds16(const ushort* g, ushort* l) {
    __builtin_amdgcn_global_load_lds(
        (const __attribute__((address_space(1))) unsigned int*)g,
        (__attribute__((address_space(3))) unsigned int*)l, 16, 0, 0);
}

// ---------------- K0: weight prep ----------------
__global__ __launch_bounds__(256) void wprep_kernel(
    const float* __restrict__ Q, const float* __restrict__ K,
    const float* __restrict__ V, const float* __restrict__ O,
    ushort* __restrict__ WhT, ushort* __restrict__ WlT,
    ushort* __restrict__ Oh, ushort* __restrict__ Ol)
{
    int n = blockIdx.x;                       // 0..255
    if (n < 192) {
        const float* W = (n < 64) ? Q : (n < 128) ? K : V;
        int c = n & 63;
        for (int k = threadIdx.x; k < DM; k += 256) {
            float w = W[k * DH + c];
            ushort hi = f2bf(w);
            WhT[n * DM + k] = hi;
            WlT[n * DM + k] = f2bf(w - bf2f(hi));
        }
    } else {
        int e0 = (n - 192) << 4;              // 16 rows of O per block
        for (int idx = threadIdx.x; idx < 16 * DH; idx += 256) {
            int off = (e0 << 6) + idx;
            float w = O[off];
            ushort hi = f2bf(w);
            Oh[off] = hi;
            Ol[off] = f2bf(w - bf2f(hi));
        }
    }
}

// ---------------- K1a: qkv partial MFMA (64-row blocks, K-split 4) ----------------
// Block = 64 seq rows x 256 k-slab, 512 thr = 8 waves: wave = (mh=w>>2, cg=w&3).
// Wave: rows (2mh+i)*16, cols cg*16 of each q/k/v. Same per-wave work as r7's
// 32-row version, but half the blocks -> half the W L2 re-staging (201->100MB).
__global__ __launch_bounds__(512) void qkv_part_kernel(
    const float* __restrict__ x, const ushort* __restrict__ WhT,
    const ushort* __restrict__ WlT, float* __restrict__ Cpart)
{
    __shared__ __align__(16) ushort Xs[2][64][34];
    __shared__ __align__(16) ushort Ws[2][192][34];
    int s0 = blockIdx.x * 64;
    int kb = blockIdx.y * 256;
    int t = threadIdx.x;
    int wave = t >> 6, lane = t & 63, m_ = lane & 15, qd = lane >> 4;
    int mh = wave >> 2, cg = wave & 3;
    const floatx4 z4 = {0.f, 0.f, 0.f, 0.f};
    floatx4 accq[2] = {z4, z4}, acck[2] = {z4, z4}, accv[2] = {z4, z4};
    int xr = t >> 3, xc = (t & 7) * 4;
    for (int k0 = 0; k0 < 256; k0 += 32) {
        float4 v = *(const float4*)&x[(size_t)(s0 + xr) * DM + kb + k0 + xc];
        ushort h0 = f2bf(v.x), h1 = f2bf(v.y), h2 = f2bf(v.z), h3 = f2bf(v.w);
        *(ushort4*)&Xs[0][xr][xc] = make_ushort4(h0, h1, h2, h3);
        *(ushort4*)&Xs[1][xr][xc] = make_ushort4(
            f2bf(v.x - bf2f(h0)), f2bf(v.y - bf2f(h1)),
            f2bf(v.z - bf2f(h2)), f2bf(v.w - bf2f(h3)));
        #pragma unroll
        for (int j = 0; j < 3; ++j) {
            int idx = t + j * 512;            // 0..1535
            int hl = (idx >= 768) ? 1 : 0;
            int r2 = idx - hl * 768;          // 0..767
            int n = r2 >> 2, kc = (r2 & 3) * 8;
            const ushort* src = hl ? WlT : WhT;
            *(uint4*)&Ws[hl][n][kc] = *(const uint4*)&src[n * DM + kb + k0 + kc];
        }
        __syncthreads();
        short8 ah[2], al[2];
        #pragma unroll
        for (int i = 0; i < 2; ++i) {
            ah[i] = *(const short8*)&Xs[0][(mh * 2 + i) * 16 + m_][qd * 8];
            al[i] = *(const short8*)&Xs[1][(mh * 2 + i) * 16 + m_][qd * 8];
        }
        int nq = cg * 16 + m_, nk = 64 + cg * 16 + m_, nv = 128 + cg * 16 + m_;
        short8 bqh = *(const short8*)&Ws[0][nq][qd * 8];
        short8 bql = *(const short8*)&Ws[1][nq][qd * 8];
        short8 bkh = *(const short8*)&Ws[0][nk][qd * 8];
        short8 bkl = *(const short8*)&Ws[1][nk][qd * 8];
        short8 bvh = *(const short8*)&Ws[0][nv][qd * 8];
        #pragma unroll
        for (int i = 0; i < 2; ++i) {
            accq[i] = __builtin_amdgcn_mfma_f32_16x16x32_bf16(ah[i], bqh, accq[i], 0, 0, 0);
            accq[i] = __builtin_amdgcn_mfma_f32_16x16x32_bf16(al[i], bqh, accq[i], 0, 0, 0);
            accq[i] = __builtin_amdgcn_mfma_f32_16x16x32_bf16(ah[i], bql, accq[i], 0, 0, 0);
            acck[i] = __builtin_amdgcn_mfma_f32_16x16x32_bf16(ah[i], bkh, acck[i], 0, 0, 0);
            acck[i] = __builtin_amdgcn_mfma_f32_16x16x32_bf16(al[i], bkh, acck[i], 0, 0, 0);
            acck[i] = __builtin_amdgcn_mfma_f32_16x16x32_bf16(ah[i], bkl, acck[i], 0, 0, 0);
            accv[i] = __builtin_amdgcn_mfma_f32_16x16x32_bf16(ah[i], bvh, accv[i], 0, 0, 0);
        }
        __syncthreads();
    }
    float* Cp = Cpart + (size_t)blockIdx.y * (NROWS * 192);
    #pragma unroll
    for (int i = 0; i < 2; ++i) {
        #pragma unroll
        for (int r = 0; r < 4; ++r) {
            int row = s0 + (mh * 2 + i) * 16 + qd * 4 + r;
            float* base = Cp + (size_t)row * 192;
            base[cg * 16 + m_]       = accq[i][r];
            base[64 + cg * 16 + m_]  = acck[i][r];
            base[128 + cg * 16 + m_] = accv[i][r];
        }
    }
}

// ---------------- K1b: reduce partials, split hi/lo, permute xv ----------------
// xvP layout [b][c32][qd][h][j8]: element = xv[c32*32 + 16*(j>>2) + 4*qd + (j&3)][h].
__global__ __launch_bounds__(256) void qkv_reduce_kernel(
    const float* __restrict__ Cpart,
    ushort* __restrict__ qh, ushort* __restrict__ ql,
    ushort* __restrict__ kh, ushort* __restrict__ kl, ushort* __restrict__ xvP)
{
    __shared__ ushort xvs[32][72];
    const size_t SL = (size_t)NROWS * 192;
    int row0 = blockIdx.x * 32;
    int t = threadIdx.x;
    #pragma unroll
    for (int i = 0; i < 24; ++i) {
        int e = i * 256 + t;
        int r = e / 192, c = e - r * 192;
        size_t row = row0 + r;
        size_t off = row * 192 + c;
        float s = Cpart[off] + Cpart[SL + off] + Cpart[2 * SL + off] + Cpart[3 * SL + off];
        ushort hi = f2bf(s);
        if (c < 64) {
            qh[row * 64 + c] = hi; ql[row * 64 + c] = f2bf(s - bf2f(hi));
        } else if (c < 128) {
            kh[row * 64 + c - 64] = hi; kl[row * 64 + c - 64] = f2bf(s - bf2f(hi));
        } else {
            xvs[r][c - 128] = hi;
        }
    }
    __syncthreads();
    int h = t & 63, qd = t >> 6;          // 4 waves <-> qd 0..3
    ushortx8 v;
    #pragma unroll
    for (int j = 0; j < 8; ++j)
        v[j] = xvs[4 * qd + (j & 3) + ((j >> 2) << 4)][h];
    int b = row0 >> 11, c32 = (row0 & 2047) >> 5;
    *(ushortx8*)&xvP[((((size_t)b << 6) + c32) * 4 + qd) * 512 + h * 8] = v;
}

// ---------------- K2: attn_part — flash attention, 4-way k-split ----------------
// (round-7 verified, unchanged)
__global__ __launch_bounds__(512) void attn_part_kernel(
    const ushort* __restrict__ qh, const ushort* __restrict__ ql,
    const ushort* __restrict__ kh, const ushort* __restrict__ kl,
    const ushort* __restrict__ xvP,
    float* __restrict__ Opart, float* __restrict__ lpart)
{
    __shared__ __align__(16) ushort Kbuf[2][8192];   // [buf][hi 4096 | lo 4096]
    __shared__ __align__(16) ushort xvbuf[2][4096];  // [buf][c32sub][qd][h][j8]
    __shared__ float lred[2][2][16];                 // [tile][h2][q]
    int bid = blockIdx.x;
    int pp = bid & 63, b = (bid >> 6) & 3, s = bid >> 8;
    int srowA = pp << 4, srowB = (127 - pp) << 4;
    int t = threadIdx.x, wave = t >> 6, lane = t & 63, m_ = lane & 15, qd = lane >> 4;
    int nA = (pp >> 2) + 1, nB = ((127 - pp) >> 2) + 1;   // nA < nB always
    int tile = wave >> 2, h2 = (wave >> 1) & 1, nh = wave & 1;
    int srow = tile ? srowB : srowA;
    int nT = tile ? nB : nA;
    int jB = (nB - s + 3) >> 2;       // nB >= 17 > 3 >= s
    const ushort* khb = kh + (((size_t)b << 11)) * 64;
    const ushort* klb = kl + (((size_t)b << 11)) * 64;
    const ushort* xvPb = xvP + ((size_t)b << 17);
    // hoisted Q B-frags: bq[hl][kk]
    short8 bq[2][2];
    {
        size_t qr = (size_t)((b << 11) + srow + m_) * 64 + qd * 8;
        bq[0][0] = *(const short8*)&qh[qr];
        bq[0][1] = *(const short8*)&qh[qr + 32];
        bq[1][0] = *(const short8*)&ql[qr];
        bq[1][1] = *(const short8*)&ql[qr + 32];
    }
    int drow = lane >> 3;                 // 0..7
    int dlc = ((lane & 7) ^ drow) * 8;    // pre-swizzled 16B chunk (ushort units)
    // stage chunk cc into buf: 24 instrs (8 K-hi, 8 K-lo, 8 xv), wave does 3
    #define AT_STAGE(cc, buf)                                                   \
        { int k0r_ = (cc) << 6;                                                 \
          _Pragma("unroll")                                                     \
          for (int i_ = 0; i_ < 3; ++i_) {                                      \
              int c_ = wave * 3 + i_;                                           \
              if (c_ < 8)                                                       \
                  load_lds16(khb + (size_t)(k0r_ + c_ * 8 + drow) * 64 + dlc,   \
                             &Kbuf[buf][c_ * 512]);                             \
              else if (c_ < 16)                                                 \
                  load_lds16(klb + (size_t)(k0r_ + (c_ - 8) * 8 + drow) * 64 + dlc, \
                             &Kbuf[buf][4096 + (c_ - 8) * 512]);                \
              else                                                              \
                  load_lds16(xvPb + (size_t)(cc) * 4096 + (c_ - 16) * 512 + lane * 8, \
                             &xvbuf[buf][(c_ - 16) * 512]);                     \
          } }
    const floatx4 z4 = {0.f, 0.f, 0.f, 0.f};
    floatx4 accO[2] = {z4, z4};
    float ll = 0.f;
    int qrow = srow + m_;
    AT_STAGE(s, 0)
    for (int j = 0; j < jB; ++j) {
        int c = s + 4 * j;
        __syncthreads();
        if (j + 1 < jB) AT_STAGE(s + 4 * (j + 1), (j + 1) & 1)
        if (c < nT) {
            int bufi = j & 1;
            floatx4 accS[2] = {z4, z4};
            #pragma unroll
            for (int kk = 0; kk < 2; ++kk) {
                #pragma unroll
                for (int tt = 0; tt < 2; ++tt) {
                    int row = (2 * h2 + tt) * 16 + m_;
                    int chunk = ((kk << 2) + qd) ^ (m_ & 7);
                    const ushort* ph = &Kbuf[bufi][row * 64 + chunk * 8];
                    short8 akh = *(const short8*)ph;
                    short8 akl = *(const short8*)(ph + 4096);
                    accS[tt] = __builtin_amdgcn_mfma_f32_16x16x32_bf16(akh, bq[0][kk], accS[tt], 0, 0, 0);
                    accS[tt] = __builtin_amdgcn_mfma_f32_16x16x32_bf16(akl, bq[0][kk], accS[tt], 0, 0, 0);
                    accS[tt] = __builtin_amdgcn_mfma_f32_16x16x32_bf16(akh, bq[1][kk], accS[tt], 0, 0, 0);
                }
            }
            float lsum = 0.f;
            short8 pa;
            #pragma unroll
            for (int tt = 0; tt < 2; ++tt) {
                #pragma unroll
                for (int r = 0; r < 4; ++r) {
                    int kc = c * 64 + (2 * h2 + tt) * 16 + qd * 4 + r;
                    float p = (kc <= qrow) ? __expf(accS[tt][r]) : 0.f;
                    lsum += p;
                    pa[tt * 4 + r] = (short)f2bf(p);
                }
            }
            if (nh == 0) ll += lsum;
            const ushort* Xb = &xvbuf[bufi][(h2 * 4 + qd) * 512];
            #pragma unroll
            for (int i = 0; i < 2; ++i) {
                int h = (nh * 2 + i) * 16 + m_;
                short8 xv = *(const short8*)&Xb[h * 8];
                accO[i] = __builtin_amdgcn_mfma_f32_16x16x32_bf16(pa, xv, accO[i], 0, 0, 0);
            }
        }
    }
    // l partial: reduce over qd lanes; (tile,h2) slot from nh==0 waves
    ll += __shfl_xor(ll, 16); ll += __shfl_xor(ll, 32);
    if (qd == 0 && nh == 0) lred[tile][h2][m_] = ll;
    __syncthreads();
    if (t < 32) {
        int tl = t >> 4, q = t & 15;
        int row = (b << 11) + (tl ? srowB : srowA) + q;
        lpart[(size_t)s * NROWS + row] = lred[tl][0][q] + lred[tl][1][q];
    }
    // O partial slab sp = s*2+h2 (disjoint rows/cols per block/wave)
    float* OP = Opart + ((size_t)(s * 2 + h2) * NROWS + (b << 11) + srow) * 64;
    #pragma unroll
    for (int i = 0; i < 2; ++i)
        #pragma unroll
        for (int r = 0; r < 4; ++r)
            OP[(qd * 4 + r) * 64 + (nh * 2 + i) * 16 + m_] = accO[i][r];
    #undef AT_STAGE
}

// ---------------- K2b: reduce slabs + scale -> bf16 hi/lo (r7 verified) ----------------
__global__ __launch_bounds__(256) void axv_reduce_kernel(
    const float* __restrict__ AxvPart, const float* __restrict__ lpart,
    ushort* __restrict__ Axvh, ushort* __restrict__ Axvl)
{
    const size_t PSL = (size_t)NROWS * DH;
    int idx = blockIdx.x * 256 + threadIdx.x;   // 131072 groups of 4
    size_t e = (size_t)idx * 4;
    int r = (int)(e >> 6);
    float4 a = *(const float4*)&AxvPart[e];
    #pragma unroll
    for (int sp = 1; sp < PVSPLIT; ++sp) {
        float4 v = *(const float4*)&AxvPart[sp * PSL + e];
        a.x += v.x; a.y += v.y; a.z += v.z; a.w += v.w;
    }
    float sc = 1.f / (lpart[r] + lpart[NROWS + r]
                    + lpart[2 * NROWS + r] + lpart[3 * NROWS + r]);
    a.x *= sc; a.y *= sc; a.z *= sc; a.w *= sc;
    ushort h0 = f2bf(a.x), h1 = f2bf(a.y), h2 = f2bf(a.z), h3 = f2bf(a.w);
    *(ushort4*)&Axvh[e] = make_ushort4(h0, h1, h2, h3);
    *(ushort4*)&Axvl[e] = make_ushort4(
        f2bf(a.x - bf2f(h0)), f2bf(a.y - bf2f(h1)),
        f2bf(a.z - bf2f(h2)), f2bf(a.w - bf2f(h3)));
}

// ---------------- K3: out = Axv @ O^T (bf16 hi/lo GEMM, r7 verified) ----------------
__global__ __launch_bounds__(256) void out_kernel(
    const ushort* __restrict__ Axvh, const ushort* __restrict__ Axvl,
    const ushort* __restrict__ Oh, const ushort* __restrict__ Ol,
    float* __restrict__ out)
{
    __shared__ __align__(16) ushort As[2][64][72];
    __shared__ __align__(16) ushort Bsh[2][128][72];
    int bid = blockIdx.x;
    int r0 = (bid >> 3) << 6;        // global row 0..8128
    int e0 = (bid & 7) << 7;         // 0..896
    int t = threadIdx.x;
    {   // A: 64 rows x 64 cols x 2 planes
        int tr = t >> 2, tc = (t & 3) << 4;
        const ushort* ah = Axvh + (size_t)(r0 + tr) * DH + tc;
        const ushort* al = Axvl + (size_t)(r0 + tr) * DH + tc;
        *(uint4*)&As[0][tr][tc]     = *(const uint4*)ah;
        *(uint4*)&As[0][tr][tc + 8] = *(const uint4*)(ah + 8);
        *(uint4*)&As[1][tr][tc]     = *(const uint4*)al;
        *(uint4*)&As[1][tr][tc + 8] = *(const uint4*)(al + 8);
    }
    {   // B: 128 rows x 64 cols x 2 planes
        int tr = t >> 1, tc = (t & 1) << 5;
        const ushort* bh = Oh + (size_t)(e0 + tr) * DH + tc;
        const ushort* bl = Ol + (size_t)(e0 + tr) * DH + tc;
        *(uint4*)&Bsh[0][tr][tc]      = *(const uint4*)bh;
        *(uint4*)&Bsh[0][tr][tc + 8]  = *(const uint4*)(bh + 8);
        *(uint4*)&Bsh[0][tr][tc + 16] = *(const uint4*)(bh + 16);
        *(uint4*)&Bsh[0][tr][tc + 24] = *(const uint4*)(bh + 24);
        *(uint4*)&Bsh[1][tr][tc]      = *(const uint4*)bl;
        *(uint4*)&Bsh[1][tr][tc + 8]  = *(const uint4*)(bl + 8);
        *(uint4*)&Bsh[1][tr][tc + 16] = *(const uint4*)(bl + 16);
        *(uint4*)&Bsh[1][tr][tc + 24] = *(const uint4*)(bl + 24);
    }
    __syncthreads();
    int wave = t >> 6, lane = t & 63, m_ = lane & 15, qd = lane >> 4;
    const floatx4 z4 = {0.f, 0.f, 0.f, 0.f};
    floatx4 acc[8] = {z4, z4, z4, z4, z4, z4, z4, z4};
    #pragma unroll
    for (int kk = 0; kk < 2; ++kk) {
        short8 ah = *(const short8*)&As[0][wave * 16 + m_][kk * 32 + qd * 8];
        short8 al = *(const short8*)&As[1][wave * 16 + m_][kk * 32 + qd * 8];
        #pragma unroll
        for (int ni = 0; ni < 8; ++ni) {
            short8 bh = *(const short8*)&Bsh[0][ni * 16 + m_][kk * 32 + qd * 8];
            short8 bl = *(const short8*)&Bsh[1][ni * 16 + m_][kk * 32 + qd * 8];
            acc[ni] = __builtin_amdgcn_mfma_f32_16x16x32_bf16(ah, bh, acc[ni], 0, 0, 0);
            acc[ni] = __builtin_amdgcn_mfma_f32_16x16x32_bf16(al, bh, acc[ni], 0, 0, 0);
            acc[ni] = __builtin_amdgcn_mfma_f32_16x16x32_bf16(ah, bl, acc[ni], 0, 0, 0);
        }
    }
    #pragma unroll
    for (int r = 0; r < 4; ++r) {
        int row = r0 + wave * 16 + qd * 4 + r;
        float* orow = out + (size_t)row * DM + e0;
        #pragma unroll
        for (int ni = 0; ni < 8; ++ni)
            orow[ni * 16 + m_] = acc[ni][r];
    }
}

extern "C" void kernel_launch(void* const* d_in, const int* in_sizes, int n_in,
                              void* d_out, int out_size, void* d_ws, size_t ws_size,
                              hipStream_t stream) {
    const float* x = (const float*)d_in[0];
    const float* Q = (const float*)d_in[1];
    const float* K = (const float*)d_in[2];
    const float* V = (const float*)d_in[3];
    const float* O = (const float*)d_in[4];
    float* out = (float*)d_out;

    char* ws = (char*)d_ws;
    ushort* qh   = (ushort*)(ws);                    // 1 MB [8192][64] bf16
    ushort* ql   = (ushort*)(ws + (1ull  << 20));
    ushort* kh   = (ushort*)(ws + (2ull  << 20));
    ushort* kl   = (ushort*)(ws + (3ull  << 20));
    ushort* xvP  = (ushort*)(ws + (4ull  << 20));    // 1 MB [4][64][4][64][8] permuted xv
    ushort* WhT  = (ushort*)(ws + (5ull  << 20));    // 384 KB [192][1024]
    ushort* WlT  = (ushort*)(ws + (5ull  << 20) + (512ull << 10));
    float*  lpart = (float*)(ws + (6ull  << 20));    // 128 KB [4][8192]
    ushort* Oh   = (ushort*)(ws + (6ull  << 20) + (256ull << 10));  // 128 KB [1024][64]
    ushort* Ol   = (ushort*)(ws + (6ull  << 20) + (384ull << 10));  // 128 KB
    float*  Opart = (float*)(ws + (7ull << 20));     // 16 MB [8][8192][64] fp32
    float*  Cpart = (float*)(ws + (23ull << 20));    // 25 MB [4][8192][192]
    // Axvh/Axvl overlap qh/ql (dead after attn_part)
    ushort* Axvh = qh;
    ushort* Axvl = ql;

    wprep_kernel<<<256, 256, 0, stream>>>(Q, K, V, O, WhT, WlT, Oh, Ol);
    qkv_part_kernel<<<dim3(NROWS / 64, 4), 512, 0, stream>>>(x, WhT, WlT, Cpart);
    qkv_reduce_kernel<<<NROWS / 32, 256, 0, stream>>>(Cpart, qh, ql, kh, kl, xvP);
    attn_part_kernel<<<64 * BATCH * 4, 512, 0, stream>>>(qh, ql, kh, kl, xvP, Opart, lpart);
    axv_reduce_kernel<<<NROWS * DH / 4 / 256, 256, 0, stream>>>(Opart, lpart, Axvh, Axvl);
    out_kernel<<<(NROWS / 64) * 8, 256, 0, stream>>>(Axvh, Axvl, Oh, Ol, out);
}